// Round 2
// baseline (408.702 us; speedup 1.0000x reference)
//
#include <hip/hip_runtime.h>
#include <math.h>

// Bit-faithful float32 replication of the JAX/XLA reference. The reference
// algorithm is chaotically sensitive for nearly-collinear edge pairs
// (t = 0/0 rounding noise occasionally lands in (0,1) and injects a spurious
// vertex). The expected output INCLUDES that f32 noise, so we must replicate
// f32 rounding exactly, not compute the true-geometry answer (f64 attempt
// scored absmax 0.129 > 0.035). __f*_rn intrinsics block FMA contraction so
// every mul/sub/div rounds exactly like XLA's elementwise HLO ops.

#define FMUL __fmul_rn
#define FADD __fadd_rn
#define FSUB __fsub_rn
#define FDIV __fdiv_rn

__global__ __launch_bounds__(256)
void riou_kernel(const float* __restrict__ pred,
                 const float* __restrict__ tgt,
                 float* __restrict__ out, int n)
{
    int i = blockIdx.x * blockDim.x + threadIdx.x;
    if (i >= n) return;

    const float* p = pred + 6 * (size_t)i;
    const float* q = tgt  + 6 * (size_t)i;

    const float px = p[0], py = p[1], pw = p[2], ph = p[3];
    const float qx = q[0], qy = q[1], qw = q[2], qh = q[3];

    // rad = atan2(s, c); cos/sin in f32 (OCML — matches jax-rocm lowering)
    float rad1 = atan2f(p[4], p[5]);
    float cA = cosf(rad1), sA = sinf(rad1);
    float rad2 = atan2f(q[4], q[5]);
    float cB = cosf(rad2), sB = sinf(rad2);

    // corners: rx = (cx*c - cy*s) + x ; ry = (cx*s + cy*c) + y
    const float ddx[4] = {0.5f, -0.5f, -0.5f, 0.5f};
    const float ddy[4] = {0.5f, 0.5f, -0.5f, -0.5f};
    float c1x[4], c1y[4], c2x[4], c2y[4];
#pragma unroll
    for (int j = 0; j < 4; j++) {
        float cx = FMUL(ddx[j], pw), cy = FMUL(ddy[j], ph);
        c1x[j] = FADD(FSUB(FMUL(cx, cA), FMUL(cy, sA)), px);
        c1y[j] = FADD(FADD(FMUL(cx, sA), FMUL(cy, cA)), py);
        float dx2 = FMUL(ddx[j], qw), dy2 = FMUL(ddy[j], qh);
        c2x[j] = FADD(FSUB(FMUL(dx2, cB), FMUL(dy2, sB)), qx);
        c2y[j] = FADD(FADD(FMUL(dx2, sB), FMUL(dy2, cB)), qy);
    }

    float fvx[24], fvy[24];
    int k = 0;
    float sx = 0.0f, sy = 0.0f;

    const float eps = 1e-6f;
    const float hi = 1.0f + 1e-6f;

    // c1 corners inside c2: p_ab = (ab.am)/(ab.ab), p_ad = (ad.am)/(ad.ad)
    {
        float ax = c2x[0], ay = c2y[0];
        float abx = FSUB(c2x[1], ax), aby = FSUB(c2y[1], ay);
        float adx = FSUB(c2x[3], ax), ady = FSUB(c2y[3], ay);
        float dab = FADD(FMUL(abx, abx), FMUL(aby, aby));
        float dad = FADD(FMUL(adx, adx), FMUL(ady, ady));
#pragma unroll
        for (int j = 0; j < 4; j++) {
            float amx = FSUB(c1x[j], ax), amy = FSUB(c1y[j], ay);
            float pab = FDIV(FADD(FMUL(abx, amx), FMUL(aby, amy)), dab);
            float pad = FDIV(FADD(FMUL(adx, amx), FMUL(ady, amy)), dad);
            if (pab > -eps && pab < hi && pad > -eps && pad < hi) {
                fvx[k] = c1x[j]; fvy[k] = c1y[j];
                sx = FADD(sx, c1x[j]); sy = FADD(sy, c1y[j]); k++;
            }
        }
    }
    // c2 corners inside c1
    {
        float ax = c1x[0], ay = c1y[0];
        float abx = FSUB(c1x[1], ax), aby = FSUB(c1y[1], ay);
        float adx = FSUB(c1x[3], ax), ady = FSUB(c1y[3], ay);
        float dab = FADD(FMUL(abx, abx), FMUL(aby, aby));
        float dad = FADD(FMUL(adx, adx), FMUL(ady, ady));
#pragma unroll
        for (int j = 0; j < 4; j++) {
            float amx = FSUB(c2x[j], ax), amy = FSUB(c2y[j], ay);
            float pab = FDIV(FADD(FMUL(abx, amx), FMUL(aby, amy)), dab);
            float pad = FDIV(FADD(FMUL(adx, amx), FMUL(ady, amy)), dad);
            if (pab > -eps && pab < hi && pad > -eps && pad < hi) {
                fvx[k] = c2x[j]; fvy[k] = c2y[j];
                sx = FADD(sx, c2x[j]); sy = FADD(sy, c2y[j]); k++;
            }
        }
    }
    // edge intersections, e1-major (c1 edge outer, c2 edge inner)
#pragma unroll
    for (int e1 = 0; e1 < 4; e1++) {
        float x1 = c1x[e1], y1 = c1y[e1];
        float x2 = c1x[(e1 + 1) & 3], y2 = c1y[(e1 + 1) & 3];
        float ex = FSUB(x2, x1), ey = FSUB(y2, y1);
#pragma unroll
        for (int e2 = 0; e2 < 4; e2++) {
            float x3 = c2x[e2], y3 = c2y[e2];
            float x4 = c2x[(e2 + 1) & 3], y4 = c2y[(e2 + 1) & 3];
            // t = ((x2-x1)(y3-y1) - (y2-y1)(x3-x1)) / ((x2-x1)(y3-y4) - (y2-y1)(x3-x4))
            float num_t = FSUB(FMUL(ex, FSUB(y3, y1)), FMUL(ey, FSUB(x3, x1)));
            float den_t = FSUB(FMUL(ex, FSUB(y3, y4)), FMUL(ey, FSUB(x3, x4)));
            float t = (den_t == 0.0f) ? -1.0f : FDIV(num_t, den_t);
            if (!(t > 0.0f && t < 1.0f)) continue;
            float fx = FSUB(x4, x3), fy = FSUB(y4, y3);
            float num_u = FSUB(FMUL(fx, FSUB(y1, y3)), FMUL(fy, FSUB(x1, x3)));
            float den_u = FSUB(FMUL(fx, FSUB(y1, y2)), FMUL(fy, FSUB(x1, x2)));
            float u = (den_u == 0.0f) ? -1.0f : FDIV(num_u, den_u);
            if (!(u > 0.0f && u < 1.0f)) continue;
            float ix = FADD(x1, FMUL(t, ex));
            float iy = FADD(y1, FMUL(t, ey));
            fvx[k] = ix; fvy[k] = iy;
            sx = FADD(sx, ix); sy = FADD(sy, iy); k++;
        }
    }

    // centroid: sum(masked verts) / max(k,1), f32 division
    float kk = (float)(k > 0 ? k : 1);
    float mx = FDIV(sx, kk), my = FDIV(sy, kk);

    // recenter + angles
    float ang[24];
    for (int j = 0; j < k; j++) {
        float vx_ = FSUB(fvx[j], mx), vy_ = FSUB(fvy[j], my);
        fvx[j] = vx_; fvy[j] = vy_;
        ang[j] = atan2f(vy_, vx_);
    }
    // stable insertion sort by angle ascending (matches jnp stable argsort
    // with identical pre-sort ordering: c1 corners, c2 corners, ints e1-major)
    for (int a = 1; a < k; a++) {
        float A = ang[a], X = fvx[a], Y = fvy[a];
        int b = a - 1;
        while (b >= 0 && ang[b] > A) {
            ang[b + 1] = ang[b]; fvx[b + 1] = fvx[b]; fvy[b + 1] = fvy[b];
            b--;
        }
        ang[b + 1] = A; fvx[b + 1] = X; fvy[b + 1] = Y;
    }
    // shoelace over k-gon == reference's padded 24-ring (pads contribute +0)
    float crs = 0.0f;
    for (int j = 0; j < k; j++) {
        int jn = (j + 1 < k) ? j + 1 : 0;
        crs = FADD(crs, FSUB(FMUL(fvx[j], fvy[jn]), FMUL(fvy[j], fvx[jn])));
    }
    float inter = FMUL(0.5f, fabsf(crs));

    float area1 = FMUL(pw, ph), area2 = FMUL(qw, qh);
    float uni = FSUB(FADD(area1, area2), inter);
    float iou = FDIV(inter, uni);

    // enclosing-box diagonal over all 8 corners
    float minx = c1x[0], maxx = c1x[0], miny = c1y[0], maxy = c1y[0];
#pragma unroll
    for (int j = 1; j < 4; j++) {
        minx = fminf(minx, c1x[j]); maxx = fmaxf(maxx, c1x[j]);
        miny = fminf(miny, c1y[j]); maxy = fmaxf(maxy, c1y[j]);
    }
#pragma unroll
    for (int j = 0; j < 4; j++) {
        minx = fminf(minx, c2x[j]); maxx = fmaxf(maxx, c2x[j]);
        miny = fminf(miny, c2y[j]); maxy = fmaxf(maxy, c2y[j]);
    }
    float wc = FSUB(maxx, minx), hc = FSUB(maxy, miny);
    float c2d = FADD(FMUL(wc, wc), FMUL(hc, hc));
    float dxc = FSUB(px, qx), dyc = FSUB(py, qy);
    float d2 = FADD(FMUL(dxc, dxc), FMUL(dyc, dyc));

    out[i] = FADD(FSUB(1.0f, iou), FDIV(d2, c2d));
}

extern "C" void kernel_launch(void* const* d_in, const int* in_sizes, int n_in,
                              void* d_out, int out_size, void* d_ws, size_t ws_size,
                              hipStream_t stream) {
    const float* pred = (const float*)d_in[0];
    const float* tgt  = (const float*)d_in[1];
    float* out = (float*)d_out;
    int n = in_sizes[0] / 6;
    int block = 256;
    int grid = (n + block - 1) / block;
    riou_kernel<<<grid, block, 0, stream>>>(pred, tgt, out, n);
}